// Round 1
// baseline (3947.400 us; speedup 1.0000x reference)
//
#include <hip/hip_runtime.h>
#include <hip/hip_bf16.h>

#define NN 102400      // B*T*NODES
#define DD 64
#define EE 1638400
#define L1C 96
#define L2C 64
#define TT 32
#define NODESC 400
#define BB 8
#define SS 3200        // B*NODES
#define G4 256         // 4*D

// ---------------- workspace layout (floats) ----------------
// big block [0, 26,214,400) holds xn -> h1 -> g1, later reused as xg
#define OFF_XN   ((size_t)0)
#define OFF_H1   ((size_t)6553600)
#define OFF_G1   ((size_t)16384000)
#define OFF_XG   ((size_t)0)
#define OFF_H2   ((size_t)26214400)
#define OFF_G2   ((size_t)32768000)
#define OFF_DIS  ((size_t)39321600)
#define OFF_WE   ((size_t)39424000)
#define OFF_HL   ((size_t)41062400)
#define OFF_ST   ((size_t)41267200)

__device__ __forceinline__ void fma4(float4& a, float s, const float4& w) {
    a.x = fmaf(s, w.x, a.x); a.y = fmaf(s, w.y, a.y);
    a.z = fmaf(s, w.z, a.z); a.w = fmaf(s, w.w, a.w);
}
__device__ __forceinline__ float sigm(float x) { return 1.f / (1.f + __expf(-x)); }

// ---------------- normalization ----------------
__global__ void zero_stats(float* st) { if (threadIdx.x < 128) st[threadIdx.x] = 0.f; }

__global__ __launch_bounds__(256) void col_sums(const float* __restrict__ x, float* __restrict__ st) {
    int c = threadIdx.x & 63;
    size_t i = (size_t)blockIdx.x * 256 + threadIdx.x;
    size_t stride = (size_t)gridDim.x * 256;
    float s = 0.f, q = 0.f;
    for (size_t e = i; e < (size_t)NN * 64; e += stride) {
        float v = x[e]; s += v; q = fmaf(v, v, q);
    }
    __shared__ float ls[128];
    if (threadIdx.x < 128) ls[threadIdx.x] = 0.f;
    __syncthreads();
    atomicAdd(&ls[c], s); atomicAdd(&ls[64 + c], q);
    __syncthreads();
    if (threadIdx.x < 128) atomicAdd(&st[threadIdx.x], ls[threadIdx.x]);
}

__global__ void finalize_stats(float* st) {
    int c = threadIdx.x;
    if (c < 64) {
        float s = st[c], q = st[64 + c];
        float mean = s / (float)NN;
        float var = (q - s * s / (float)NN) / (float)(NN - 1);
        st[128 + c] = mean;
        st[192 + c] = rsqrtf(fmaxf(var, 1e-20f));
    }
}

__global__ __launch_bounds__(256) void normalize_k(const float* __restrict__ x, const float* __restrict__ st, float* __restrict__ xn) {
    size_t i = (size_t)blockIdx.x * 256 + threadIdx.x;   // float4 index
    int c = ((int)(i & 15)) * 4;
    float4 v = ((const float4*)x)[i];
    const float* mean = st + 128; const float* istd = st + 192;
    v.x = (v.x - mean[c + 0]) * istd[c + 0];
    v.y = (v.y - mean[c + 1]) * istd[c + 1];
    v.z = (v.z - mean[c + 2]) * istd[c + 2];
    v.w = (v.w - mean[c + 3]) * istd[c + 3];
    ((float4*)xn)[i] = v;
}

// ---------------- degree / edge weights ----------------
__global__ void deg_init(float* dis) { dis[(size_t)blockIdx.x * 256 + threadIdx.x] = 1.f; }

__global__ void deg_acc(const float* __restrict__ ea, const int* __restrict__ ei, float* __restrict__ dis) {
    size_t e = (size_t)blockIdx.x * 256 + threadIdx.x;
    atomicAdd(&dis[ei[EE + e]], fabsf(ea[2 * e]));
}

__global__ void deg_finish(float* dis) {
    size_t n = (size_t)blockIdx.x * 256 + threadIdx.x;
    dis[n] = rsqrtf(dis[n]);
}

__global__ void edge_w(const float* __restrict__ ea, const int* __restrict__ ei, const float* __restrict__ dis, float* __restrict__ we) {
    size_t e = (size_t)blockIdx.x * 256 + threadIdx.x;
    int s = ei[e], d = ei[EE + e];
    we[e] = dis[s] * fabsf(ea[2 * e]) * dis[d];
}

// ---------------- tiled f32 GEMM ----------------
// C[M x NC] = (prelu? relu(A+bin) : A)[M x K] @ W[K x NC]; optional transposed W (w_ih) and
// permuted "xg" output with bias bo1+bo2.
template<int K, int NC, int MB, int THREADS, bool PRELU, bool TRANSW, bool XGOUT>
__global__ __launch_bounds__(THREADS) void gemm_tiled(
    const float* __restrict__ A, const float* __restrict__ Wm,
    const float* __restrict__ bin, const float* __restrict__ bo1, const float* __restrict__ bo2,
    float* __restrict__ Cm, int ldC, int col0)
{
    __shared__ float As[MB * K];
    __shared__ float Ws[K * NC];

    if (!TRANSW) {
        for (int i = threadIdx.x; i < K * NC / 4; i += THREADS)
            ((float4*)Ws)[i] = ((const float4*)Wm)[i];
    } else {
        for (int i = threadIdx.x; i < NC * (K / 4); i += THREADS) {
            int g = i / (K / 4); int d = (i % (K / 4)) * 4;
            float4 v = *(const float4*)(Wm + (size_t)(col0 + g) * K + d);
            Ws[(d + 0) * NC + g] = v.x; Ws[(d + 1) * NC + g] = v.y;
            Ws[(d + 2) * NC + g] = v.z; Ws[(d + 3) * NC + g] = v.w;
        }
    }
    size_t row0 = (size_t)blockIdx.x * MB;
    for (int i = threadIdx.x; i < MB * (K / 4); i += THREADS) {
        int r = i / (K / 4); int c = (i % (K / 4)) * 4;
        float4 a = *(const float4*)(A + (row0 + r) * K + c);
        if (PRELU) {
            a.x = fmaxf(a.x + bin[c + 0], 0.f); a.y = fmaxf(a.y + bin[c + 1], 0.f);
            a.z = fmaxf(a.z + bin[c + 2], 0.f); a.w = fmaxf(a.w + bin[c + 3], 0.f);
        }
        ((float4*)As)[i] = a;
    }
    __syncthreads();

    constexpr int NCT = NC / 4;
    int tc = threadIdx.x % NCT;
    int tr = threadIdx.x / NCT;
    int r = tr * 4;
    float4 acc[4];
    acc[0] = acc[1] = acc[2] = acc[3] = make_float4(0.f, 0.f, 0.f, 0.f);

    #pragma unroll 8
    for (int d4 = 0; d4 < K / 4; ++d4) {
        float4 w0 = ((const float4*)Ws)[(4 * d4 + 0) * NCT + tc];
        float4 w1 = ((const float4*)Ws)[(4 * d4 + 1) * NCT + tc];
        float4 w2 = ((const float4*)Ws)[(4 * d4 + 2) * NCT + tc];
        float4 w3 = ((const float4*)Ws)[(4 * d4 + 3) * NCT + tc];
        #pragma unroll
        for (int i = 0; i < 4; ++i) {
            float4 av = ((const float4*)As)[(r + i) * (K / 4) + d4];
            fma4(acc[i], av.x, w0); fma4(acc[i], av.y, w1);
            fma4(acc[i], av.z, w2); fma4(acc[i], av.w, w3);
        }
    }

    if (!XGOUT) {
        #pragma unroll
        for (int i = 0; i < 4; ++i) {
            size_t row = row0 + r + i;
            *(float4*)(Cm + row * ldC + tc * 4) = acc[i];
        }
    } else {
        int cb = col0 + tc * 4;
        float4 bs;
        bs.x = bo1[cb + 0] + bo2[cb + 0]; bs.y = bo1[cb + 1] + bo2[cb + 1];
        bs.z = bo1[cb + 2] + bo2[cb + 2]; bs.w = bo1[cb + 3] + bo2[cb + 3];
        #pragma unroll
        for (int i = 0; i < 4; ++i) {
            int n = (int)row0 + r + i;                      // n = b*T*NODES + t*NODES + node
            int b_ = n / (TT * NODESC);
            int rem = n - b_ * (TT * NODESC);
            int t = rem / NODESC;
            int node = rem - t * NODESC;
            int orow = (b_ * NODESC + node) * TT + t;       // seq-major, time inner
            float4 o = acc[i];
            o.x += bs.x; o.y += bs.y; o.z += bs.z; o.w += bs.w;
            *(float4*)(Cm + (size_t)orow * ldC + cb) = o;
        }
    }
}

// ---------------- GCN aggregation ----------------
template<int C>
__global__ __launch_bounds__(256) void self_init(const float* __restrict__ h, const float* __restrict__ dis, float* __restrict__ g) {
    size_t i = (size_t)blockIdx.x * 256 + threadIdx.x;   // float4 index
    int n = (int)(i / (C / 4));
    float d = dis[n]; float dd = d * d;
    float4 v = ((const float4*)h)[i];
    v.x *= dd; v.y *= dd; v.z *= dd; v.w *= dd;
    ((float4*)g)[i] = v;
}

template<int C4>
__global__ __launch_bounds__(256) void edge_scatter(const float* __restrict__ h, const int* __restrict__ ei,
                                                    const float* __restrict__ we, float* __restrict__ g) {
    unsigned int idx = blockIdx.x * 256 + threadIdx.x;
    unsigned int e = idx / C4; unsigned int q = idx % C4;
    int s = ei[e], d = ei[EE + e];
    float w = we[e];
    float4 v = ((const float4*)h)[(size_t)s * C4 + q];
    float* gd = g + (size_t)d * (C4 * 4) + q * 4;
    atomicAdd(gd + 0, v.x * w); atomicAdd(gd + 1, v.y * w);
    atomicAdd(gd + 2, v.z * w); atomicAdd(gd + 3, v.w * w);
}

// ---------------- LSTM (recurrent part; xg precomputed) ----------------
// block = 256 threads = 4 waves; wave w = gate type (i,f,g,o); lane j = hidden unit.
// Each lane keeps its w_hh row (64 f32) in VGPRs; h broadcast from LDS.
__global__ __launch_bounds__(256) void lstm_kernel(const float* __restrict__ xg, const float* __restrict__ whh,
                                                   float* __restrict__ hlast) {
    constexpr int QS = 4;
    __shared__ float hs[QS][64];
    __shared__ float cs[QS][64];
    __shared__ float gp[QS][256];
    int tid = threadIdx.x;
    int w = tid >> 6, j = tid & 63;
    int row = w * 64 + j;
    float4 wv[16];
    const float4* wr = (const float4*)(whh + (size_t)row * 64);
    #pragma unroll
    for (int d4 = 0; d4 < 16; ++d4) wv[d4] = wr[d4];
    hs[w][j] = 0.f; cs[w][j] = 0.f;
    __syncthreads();
    size_t s0 = (size_t)blockIdx.x * QS;
    for (int t = 0; t < TT; ++t) {
        #pragma unroll
        for (int q = 0; q < QS; ++q) {
            const float4* hq = (const float4*)hs[q];
            float4 acc = make_float4(0.f, 0.f, 0.f, 0.f);
            #pragma unroll
            for (int d4 = 0; d4 < 16; ++d4) {
                float4 hv = hq[d4];
                acc.x = fmaf(hv.x, wv[d4].x, acc.x); acc.y = fmaf(hv.y, wv[d4].y, acc.y);
                acc.z = fmaf(hv.z, wv[d4].z, acc.z); acc.w = fmaf(hv.w, wv[d4].w, acc.w);
            }
            float dot = (acc.x + acc.y) + (acc.z + acc.w);
            float pre = xg[((s0 + q) * TT + t) * G4 + row] + dot;
            gp[q][row] = pre;
        }
        __syncthreads();
        {
            int q = w;
            float gi = gp[q][j], gf = gp[q][64 + j], gg = gp[q][128 + j], go = gp[q][192 + j];
            float c = sigm(gf) * cs[q][j] + sigm(gi) * tanhf(gg);
            float h = sigm(go) * tanhf(c);
            cs[q][j] = c; hs[q][j] = h;
        }
        __syncthreads();
    }
    hlast[(s0 + w) * 64 + j] = hs[w][j];
}

// ---------------- FC head + softmax ----------------
__global__ __launch_bounds__(128) void head_kernel(const float* __restrict__ hl,
                                                   const float* __restrict__ w1, const float* __restrict__ b1,
                                                   const float* __restrict__ w2, const float* __restrict__ b2,
                                                   float* __restrict__ out) {
    __shared__ float hrow[64];
    __shared__ float a1[128];
    __shared__ float lg[3];
    int s = blockIdx.x, tid = threadIdx.x;
    if (tid < 64) hrow[tid] = hl[(size_t)s * 64 + tid];
    __syncthreads();
    {
        const float4* wr = (const float4*)(w1 + (size_t)tid * 64);
        const float4* hq = (const float4*)hrow;
        float4 acc = make_float4(0.f, 0.f, 0.f, 0.f);
        #pragma unroll
        for (int k = 0; k < 16; ++k) {
            float4 wv = wr[k]; float4 hv = hq[k];
            acc.x = fmaf(wv.x, hv.x, acc.x); acc.y = fmaf(wv.y, hv.y, acc.y);
            acc.z = fmaf(wv.z, hv.z, acc.z); acc.w = fmaf(wv.w, hv.w, acc.w);
        }
        a1[tid] = fmaxf((acc.x + acc.y) + (acc.z + acc.w) + b1[tid], 0.f);
    }
    __syncthreads();
    if (tid < 3) {
        const float4* wr = (const float4*)(w2 + (size_t)tid * 128);
        const float4* aq = (const float4*)a1;
        float4 acc = make_float4(0.f, 0.f, 0.f, 0.f);
        #pragma unroll
        for (int k = 0; k < 32; ++k) {
            float4 wv = wr[k]; float4 av = aq[k];
            acc.x = fmaf(wv.x, av.x, acc.x); acc.y = fmaf(wv.y, av.y, acc.y);
            acc.z = fmaf(wv.z, av.z, acc.z); acc.w = fmaf(wv.w, av.w, acc.w);
        }
        lg[tid] = (acc.x + acc.y) + (acc.z + acc.w) + b2[tid];
    }
    __syncthreads();
    if (tid == 0) {
        float m = fmaxf(lg[0], fmaxf(lg[1], lg[2]));
        float e0 = __expf(lg[0] - m), e1 = __expf(lg[1] - m), e2 = __expf(lg[2] - m);
        float inv = 1.f / (e0 + e1 + e2);
        out[(size_t)s * 3 + 0] = e0 * inv;
        out[(size_t)s * 3 + 1] = e1 * inv;
        out[(size_t)s * 3 + 2] = e2 * inv;
    }
}

extern "C" void kernel_launch(void* const* d_in, const int* in_sizes, int n_in,
                              void* d_out, int out_size, void* d_ws, size_t ws_size,
                              hipStream_t stream) {
    (void)in_sizes; (void)n_in; (void)out_size; (void)ws_size;
    const float* x        = (const float*)d_in[0];
    const float* ea       = (const float*)d_in[1];
    const float* conv1_w  = (const float*)d_in[2];
    const float* conv1_b  = (const float*)d_in[3];
    const float* conv2_w  = (const float*)d_in[4];
    const float* conv2_b  = (const float*)d_in[5];
    const float* w_ih     = (const float*)d_in[6];
    const float* w_hh     = (const float*)d_in[7];
    const float* b_ih     = (const float*)d_in[8];
    const float* b_hh     = (const float*)d_in[9];
    const float* fc1_w    = (const float*)d_in[10];
    const float* fc1_b    = (const float*)d_in[11];
    const float* fc2_w    = (const float*)d_in[12];
    const float* fc2_b    = (const float*)d_in[13];
    const int*   ei       = (const int*)d_in[14];
    float* out = (float*)d_out;

    float* W   = (float*)d_ws;
    float* xn  = W + OFF_XN;
    float* h1  = W + OFF_H1;
    float* g1  = W + OFF_G1;
    float* xg  = W + OFF_XG;
    float* h2  = W + OFF_H2;
    float* g2  = W + OFF_G2;
    float* dis = W + OFF_DIS;
    float* we  = W + OFF_WE;
    float* hl  = W + OFF_HL;
    float* st  = W + OFF_ST;

    // normalization
    zero_stats<<<1, 256, 0, stream>>>(st);
    col_sums<<<1024, 256, 0, stream>>>(x, st);
    finalize_stats<<<1, 64, 0, stream>>>(st);
    normalize_k<<<NN * 64 / 4 / 256, 256, 0, stream>>>(x, st, xn);

    // degrees / edge weights (shared across both GCN layers)
    deg_init<<<NN / 256, 256, 0, stream>>>(dis);
    deg_acc<<<EE / 256, 256, 0, stream>>>(ea, ei, dis);
    deg_finish<<<NN / 256, 256, 0, stream>>>(dis);
    edge_w<<<EE / 256, 256, 0, stream>>>(ea, ei, dis, we);

    // GCN layer 1: h1 = xn @ W1 ; g1 = scatter + self ; (bias+relu fused into next GEMM load)
    gemm_tiled<64, 96, 32, 192, false, false, false><<<NN / 32, 192, 0, stream>>>(
        xn, conv1_w, nullptr, nullptr, nullptr, h1, 96, 0);
    self_init<96><<<NN * 24 / 256, 256, 0, stream>>>(h1, dis, g1);
    edge_scatter<24><<<EE * 24 / 256, 256, 0, stream>>>(h1, ei, we, g1);

    // GCN layer 2: h2 = relu(g1+b1) @ W2 ; g2 = scatter + self
    gemm_tiled<96, 64, 64, 256, true, false, false><<<NN / 64, 256, 0, stream>>>(
        g1, conv2_w, conv1_b, nullptr, nullptr, h2, 64, 0);
    self_init<64><<<NN * 16 / 256, 256, 0, stream>>>(h2, dis, g2);
    edge_scatter<16><<<EE * 16 / 256, 256, 0, stream>>>(h2, ei, we, g2);

    // LSTM input transform: xg[(s*T+t)*256 + g] = relu(g2+b2) @ w_ih^T + b_ih + b_hh
    // (xg aliases the dead xn/h1/g1 block)
    gemm_tiled<64, 128, 32, 256, true, true, true><<<NN / 32, 256, 0, stream>>>(
        g2, w_ih, conv2_b, b_ih, b_hh, xg, 256, 0);
    gemm_tiled<64, 128, 32, 256, true, true, true><<<NN / 32, 256, 0, stream>>>(
        g2, w_ih, conv2_b, b_ih, b_hh, xg, 256, 128);

    // LSTM recurrence
    lstm_kernel<<<SS / 4, 256, 0, stream>>>(xg, w_hh, hl);

    // FC head + softmax
    head_kernel<<<SS, 128, 0, stream>>>(hl, fc1_w, fc1_b, fc2_w, fc2_b, out);
}

// Round 2
// 909.740 us; speedup vs baseline: 4.3390x; 4.3390x over previous
//
#include <hip/hip_runtime.h>
#include <hip/hip_bf16.h>

#define NN 102400      // B*T*NODES
#define DD 64
#define EE 1638400
#define L1C 96
#define L2C 64
#define TT 32
#define NODESC 400
#define BB 8
#define SS 3200        // B*NODES
#define G4 256         // 4*D

// ---------------- workspace layout (floats) ----------------
// big block [0, 26,214,400) holds xn -> (csr after gemm1) -> later reused as xg
#define OFF_XN   ((size_t)0)
#define OFF_H1   ((size_t)6553600)
#define OFF_G1   ((size_t)16384000)
#define OFF_XG   ((size_t)0)
#define OFF_H2   ((size_t)26214400)
#define OFF_G2   ((size_t)32768000)
#define OFF_DIS  ((size_t)39321600)
#define OFF_WE   ((size_t)39424000)
#define OFF_HL   ((size_t)41062400)
#define OFF_ST   ((size_t)41267200)
// CSR arrays live in the dead xn region [0, 6,553,600) once gemm1 has consumed xn
#define OFF_ROFF ((size_t)0)          // NN+1 ints
#define OFF_CUR  ((size_t)102416)     // NN ints
#define OFF_CSRC ((size_t)204816)     // EE ints
#define OFF_CSW  ((size_t)1843216)    // EE floats   (ends at 3,481,616 < 6,553,600)

__device__ __forceinline__ void fma4(float4& a, float s, const float4& w) {
    a.x = fmaf(s, w.x, a.x); a.y = fmaf(s, w.y, a.y);
    a.z = fmaf(s, w.z, a.z); a.w = fmaf(s, w.w, a.w);
}
__device__ __forceinline__ float sigm(float x) { return 1.f / (1.f + __expf(-x)); }

// ---------------- normalization ----------------
__global__ void zero_stats(float* st) { if (threadIdx.x < 128) st[threadIdx.x] = 0.f; }

__global__ __launch_bounds__(256) void col_sums(const float* __restrict__ x, float* __restrict__ st) {
    int c = threadIdx.x & 63;
    size_t i = (size_t)blockIdx.x * 256 + threadIdx.x;
    size_t stride = (size_t)gridDim.x * 256;
    float s = 0.f, q = 0.f;
    for (size_t e = i; e < (size_t)NN * 64; e += stride) {
        float v = x[e]; s += v; q = fmaf(v, v, q);
    }
    __shared__ float ls[128];
    if (threadIdx.x < 128) ls[threadIdx.x] = 0.f;
    __syncthreads();
    atomicAdd(&ls[c], s); atomicAdd(&ls[64 + c], q);
    __syncthreads();
    if (threadIdx.x < 128) atomicAdd(&st[threadIdx.x], ls[threadIdx.x]);
}

__global__ void finalize_stats(float* st) {
    int c = threadIdx.x;
    if (c < 64) {
        float s = st[c], q = st[64 + c];
        float mean = s / (float)NN;
        float var = (q - s * s / (float)NN) / (float)(NN - 1);
        st[128 + c] = mean;
        st[192 + c] = rsqrtf(fmaxf(var, 1e-20f));
    }
}

__global__ __launch_bounds__(256) void normalize_k(const float* __restrict__ x, const float* __restrict__ st, float* __restrict__ xn) {
    size_t i = (size_t)blockIdx.x * 256 + threadIdx.x;   // float4 index
    int c = ((int)(i & 15)) * 4;
    float4 v = ((const float4*)x)[i];
    const float* mean = st + 128; const float* istd = st + 192;
    v.x = (v.x - mean[c + 0]) * istd[c + 0];
    v.y = (v.y - mean[c + 1]) * istd[c + 1];
    v.z = (v.z - mean[c + 2]) * istd[c + 2];
    v.w = (v.w - mean[c + 3]) * istd[c + 3];
    ((float4*)xn)[i] = v;
}

// ---------------- degree / edge weights ----------------
__global__ void deg_init(float* dis) { dis[(size_t)blockIdx.x * 256 + threadIdx.x] = 1.f; }

__global__ void deg_acc(const float* __restrict__ ea, const int* __restrict__ ei, float* __restrict__ dis) {
    size_t e = (size_t)blockIdx.x * 256 + threadIdx.x;
    atomicAdd(&dis[ei[EE + e]], fabsf(ea[2 * e]));
}

__global__ void deg_finish(float* dis) {
    size_t n = (size_t)blockIdx.x * 256 + threadIdx.x;
    dis[n] = rsqrtf(dis[n]);
}

__global__ void edge_w(const float* __restrict__ ea, const int* __restrict__ ei, const float* __restrict__ dis, float* __restrict__ we) {
    size_t e = (size_t)blockIdx.x * 256 + threadIdx.x;
    int s = ei[e], d = ei[EE + e];
    we[e] = dis[s] * fabsf(ea[2 * e]) * dis[d];
}

// ---------------- CSR build (dest-sorted edge list; kills all float atomics) ----------------
__global__ void hist_zero(int* cnt) { cnt[blockIdx.x * 256 + threadIdx.x] = 0; }

__global__ void hist_acc(const int* __restrict__ ei, int* __restrict__ cnt) {
    int e = blockIdx.x * 256 + threadIdx.x;
    atomicAdd(&cnt[ei[EE + e]], 1);
}

// single-block exclusive scan over NN counts; writes roff[0..NN] and cursor[0..NN-1]
__global__ __launch_bounds__(1024) void scan_kernel(int* __restrict__ cnt, int* __restrict__ roff, int* __restrict__ cursor) {
    __shared__ int part[1024];
    int tid = threadIdx.x;
    int base = tid * (NN / 1024);
    int s = 0;
    for (int i = 0; i < NN / 1024; ++i) s += cnt[base + i];
    part[tid] = s;
    __syncthreads();
    for (int d = 1; d < 1024; d <<= 1) {
        int v = (tid >= d) ? part[tid - d] : 0;
        __syncthreads();
        part[tid] += v;
        __syncthreads();
    }
    int run = part[tid] - s;     // exclusive prefix of this thread's range
    for (int i = 0; i < NN / 1024; ++i) {
        int c = cnt[base + i];
        roff[base + i] = run;
        cursor[base + i] = run;
        run += c;
    }
    if (tid == 1023) roff[NN] = run;
}

__global__ void csr_fill(const int* __restrict__ ei, const float* __restrict__ we,
                         int* __restrict__ cursor, int* __restrict__ csr_src, float* __restrict__ csr_w) {
    int e = blockIdx.x * 256 + threadIdx.x;
    int d = ei[EE + e];
    int pos = atomicAdd(&cursor[d], 1);
    csr_src[pos] = ei[e];
    csr_w[pos] = we[e];
}

// ---------------- tiled f32 GEMM ----------------
template<int K, int NC, int MB, int THREADS, bool PRELU, bool TRANSW, bool XGOUT>
__global__ __launch_bounds__(THREADS) void gemm_tiled(
    const float* __restrict__ A, const float* __restrict__ Wm,
    const float* __restrict__ bin, const float* __restrict__ bo1, const float* __restrict__ bo2,
    float* __restrict__ Cm, int ldC, int col0)
{
    __shared__ float As[MB * K];
    __shared__ float Ws[K * NC];

    if (!TRANSW) {
        for (int i = threadIdx.x; i < K * NC / 4; i += THREADS)
            ((float4*)Ws)[i] = ((const float4*)Wm)[i];
    } else {
        for (int i = threadIdx.x; i < NC * (K / 4); i += THREADS) {
            int g = i / (K / 4); int d = (i % (K / 4)) * 4;
            float4 v = *(const float4*)(Wm + (size_t)(col0 + g) * K + d);
            Ws[(d + 0) * NC + g] = v.x; Ws[(d + 1) * NC + g] = v.y;
            Ws[(d + 2) * NC + g] = v.z; Ws[(d + 3) * NC + g] = v.w;
        }
    }
    size_t row0 = (size_t)blockIdx.x * MB;
    for (int i = threadIdx.x; i < MB * (K / 4); i += THREADS) {
        int r = i / (K / 4); int c = (i % (K / 4)) * 4;
        float4 a = *(const float4*)(A + (row0 + r) * K + c);
        if (PRELU) {
            a.x = fmaxf(a.x + bin[c + 0], 0.f); a.y = fmaxf(a.y + bin[c + 1], 0.f);
            a.z = fmaxf(a.z + bin[c + 2], 0.f); a.w = fmaxf(a.w + bin[c + 3], 0.f);
        }
        ((float4*)As)[i] = a;
    }
    __syncthreads();

    constexpr int NCT = NC / 4;
    int tc = threadIdx.x % NCT;
    int tr = threadIdx.x / NCT;
    int r = tr * 4;
    float4 acc[4];
    acc[0] = acc[1] = acc[2] = acc[3] = make_float4(0.f, 0.f, 0.f, 0.f);

    #pragma unroll 8
    for (int d4 = 0; d4 < K / 4; ++d4) {
        float4 w0 = ((const float4*)Ws)[(4 * d4 + 0) * NCT + tc];
        float4 w1 = ((const float4*)Ws)[(4 * d4 + 1) * NCT + tc];
        float4 w2 = ((const float4*)Ws)[(4 * d4 + 2) * NCT + tc];
        float4 w3 = ((const float4*)Ws)[(4 * d4 + 3) * NCT + tc];
        #pragma unroll
        for (int i = 0; i < 4; ++i) {
            float4 av = ((const float4*)As)[(r + i) * (K / 4) + d4];
            fma4(acc[i], av.x, w0); fma4(acc[i], av.y, w1);
            fma4(acc[i], av.z, w2); fma4(acc[i], av.w, w3);
        }
    }

    if (!XGOUT) {
        #pragma unroll
        for (int i = 0; i < 4; ++i) {
            size_t row = row0 + r + i;
            *(float4*)(Cm + row * ldC + tc * 4) = acc[i];
        }
    } else {
        int cb = col0 + tc * 4;
        float4 bs;
        bs.x = bo1[cb + 0] + bo2[cb + 0]; bs.y = bo1[cb + 1] + bo2[cb + 1];
        bs.z = bo1[cb + 2] + bo2[cb + 2]; bs.w = bo1[cb + 3] + bo2[cb + 3];
        #pragma unroll
        for (int i = 0; i < 4; ++i) {
            int n = (int)row0 + r + i;                      // n = b*T*NODES + t*NODES + node
            int b_ = n / (TT * NODESC);
            int rem = n - b_ * (TT * NODESC);
            int t = rem / NODESC;
            int node = rem - t * NODESC;
            int orow = (b_ * NODESC + node) * TT + t;       // seq-major, time inner
            float4 o = acc[i];
            o.x += bs.x; o.y += bs.y; o.z += bs.z; o.w += bs.w;
            *(float4*)(Cm + (size_t)orow * ldC + cb) = o;
        }
    }
}

// ---------------- GCN aggregation: gather over CSR (no atomics) ----------------
// C4/ threads per destination node; thread q accumulates float4 chunk q.
// Self-loop term (weight dis[n]^2) folded in.
template<int C4>
__global__ __launch_bounds__(256) void gcn_gather(const float* __restrict__ h, const int* __restrict__ roff,
                                                  const int* __restrict__ csr_src, const float* __restrict__ csr_w,
                                                  const float* __restrict__ dis, float* __restrict__ g) {
    unsigned int idx = blockIdx.x * 256 + threadIdx.x;
    unsigned int n = idx / C4, q = idx % C4;
    float d = dis[n]; float dd = d * d;
    float4 acc = ((const float4*)h)[(size_t)n * C4 + q];
    acc.x *= dd; acc.y *= dd; acc.z *= dd; acc.w *= dd;
    int e0 = roff[n], e1 = roff[n + 1];
    for (int e = e0; e < e1; ++e) {
        int s = csr_src[e];
        float w = csr_w[e];
        float4 v = ((const float4*)h)[(size_t)s * C4 + q];
        fma4(acc, w, v);
    }
    ((float4*)g)[(size_t)n * C4 + q] = acc;
}

// ---------------- LSTM (recurrent part; xg precomputed) ----------------
__global__ __launch_bounds__(256) void lstm_kernel(const float* __restrict__ xg, const float* __restrict__ whh,
                                                   float* __restrict__ hlast) {
    constexpr int QS = 4;
    __shared__ float hs[QS][64];
    __shared__ float cs[QS][64];
    __shared__ float gp[QS][256];
    int tid = threadIdx.x;
    int w = tid >> 6, j = tid & 63;
    int row = w * 64 + j;
    float4 wv[16];
    const float4* wr = (const float4*)(whh + (size_t)row * 64);
    #pragma unroll
    for (int d4 = 0; d4 < 16; ++d4) wv[d4] = wr[d4];
    hs[w][j] = 0.f; cs[w][j] = 0.f;
    __syncthreads();
    size_t s0 = (size_t)blockIdx.x * QS;
    for (int t = 0; t < TT; ++t) {
        #pragma unroll
        for (int q = 0; q < QS; ++q) {
            const float4* hq = (const float4*)hs[q];
            float4 acc = make_float4(0.f, 0.f, 0.f, 0.f);
            #pragma unroll
            for (int d4 = 0; d4 < 16; ++d4) {
                float4 hv = hq[d4];
                acc.x = fmaf(hv.x, wv[d4].x, acc.x); acc.y = fmaf(hv.y, wv[d4].y, acc.y);
                acc.z = fmaf(hv.z, wv[d4].z, acc.z); acc.w = fmaf(hv.w, wv[d4].w, acc.w);
            }
            float dot = (acc.x + acc.y) + (acc.z + acc.w);
            float pre = xg[((s0 + q) * TT + t) * G4 + row] + dot;
            gp[q][row] = pre;
        }
        __syncthreads();
        {
            int q = w;
            float gi = gp[q][j], gf = gp[q][64 + j], gg = gp[q][128 + j], go = gp[q][192 + j];
            float c = sigm(gf) * cs[q][j] + sigm(gi) * tanhf(gg);
            float h = sigm(go) * tanhf(c);
            cs[q][j] = c; hs[q][j] = h;
        }
        __syncthreads();
    }
    hlast[(s0 + w) * 64 + j] = hs[w][j];
}

// ---------------- FC head + softmax ----------------
__global__ __launch_bounds__(128) void head_kernel(const float* __restrict__ hl,
                                                   const float* __restrict__ w1, const float* __restrict__ b1,
                                                   const float* __restrict__ w2, const float* __restrict__ b2,
                                                   float* __restrict__ out) {
    __shared__ float hrow[64];
    __shared__ float a1[128];
    __shared__ float lg[3];
    int s = blockIdx.x, tid = threadIdx.x;
    if (tid < 64) hrow[tid] = hl[(size_t)s * 64 + tid];
    __syncthreads();
    {
        const float4* wr = (const float4*)(w1 + (size_t)tid * 64);
        const float4* hq = (const float4*)hrow;
        float4 acc = make_float4(0.f, 0.f, 0.f, 0.f);
        #pragma unroll
        for (int k = 0; k < 16; ++k) {
            float4 wv = wr[k]; float4 hv = hq[k];
            acc.x = fmaf(wv.x, hv.x, acc.x); acc.y = fmaf(wv.y, hv.y, acc.y);
            acc.z = fmaf(wv.z, hv.z, acc.z); acc.w = fmaf(wv.w, hv.w, acc.w);
        }
        a1[tid] = fmaxf((acc.x + acc.y) + (acc.z + acc.w) + b1[tid], 0.f);
    }
    __syncthreads();
    if (tid < 3) {
        const float4* wr = (const float4*)(w2 + (size_t)tid * 128);
        const float4* aq = (const float4*)a1;
        float4 acc = make_float4(0.f, 0.f, 0.f, 0.f);
        #pragma unroll
        for (int k = 0; k < 32; ++k) {
            float4 wv = wr[k]; float4 av = aq[k];
            acc.x = fmaf(wv.x, av.x, acc.x); acc.y = fmaf(wv.y, av.y, acc.y);
            acc.z = fmaf(wv.z, av.z, acc.z); acc.w = fmaf(wv.w, av.w, acc.w);
        }
        lg[tid] = (acc.x + acc.y) + (acc.z + acc.w) + b2[tid];
    }
    __syncthreads();
    if (tid == 0) {
        float m = fmaxf(lg[0], fmaxf(lg[1], lg[2]));
        float e0 = __expf(lg[0] - m), e1 = __expf(lg[1] - m), e2 = __expf(lg[2] - m);
        float inv = 1.f / (e0 + e1 + e2);
        out[(size_t)s * 3 + 0] = e0 * inv;
        out[(size_t)s * 3 + 1] = e1 * inv;
        out[(size_t)s * 3 + 2] = e2 * inv;
    }
}

extern "C" void kernel_launch(void* const* d_in, const int* in_sizes, int n_in,
                              void* d_out, int out_size, void* d_ws, size_t ws_size,
                              hipStream_t stream) {
    (void)in_sizes; (void)n_in; (void)out_size; (void)ws_size;
    const float* x        = (const float*)d_in[0];
    const float* ea       = (const float*)d_in[1];
    const float* conv1_w  = (const float*)d_in[2];
    const float* conv1_b  = (const float*)d_in[3];
    const float* conv2_w  = (const float*)d_in[4];
    const float* conv2_b  = (const float*)d_in[5];
    const float* w_ih     = (const float*)d_in[6];
    const float* w_hh     = (const float*)d_in[7];
    const float* b_ih     = (const float*)d_in[8];
    const float* b_hh     = (const float*)d_in[9];
    const float* fc1_w    = (const float*)d_in[10];
    const float* fc1_b    = (const float*)d_in[11];
    const float* fc2_w    = (const float*)d_in[12];
    const float* fc2_b    = (const float*)d_in[13];
    const int*   ei       = (const int*)d_in[14];
    float* out = (float*)d_out;

    float* W   = (float*)d_ws;
    float* xn  = W + OFF_XN;
    float* h1  = W + OFF_H1;
    float* g1  = W + OFF_G1;
    float* xg  = W + OFF_XG;
    float* h2  = W + OFF_H2;
    float* g2  = W + OFF_G2;
    float* dis = W + OFF_DIS;
    float* we  = W + OFF_WE;
    float* hl  = W + OFF_HL;
    float* st  = W + OFF_ST;
    int*   roff    = (int*)(W + OFF_ROFF);
    int*   cursor  = (int*)(W + OFF_CUR);
    int*   csr_src = (int*)(W + OFF_CSRC);
    float* csr_w   = W + OFF_CSW;

    // normalization
    zero_stats<<<1, 256, 0, stream>>>(st);
    col_sums<<<1024, 256, 0, stream>>>(x, st);
    finalize_stats<<<1, 64, 0, stream>>>(st);
    normalize_k<<<NN * 64 / 4 / 256, 256, 0, stream>>>(x, st, xn);

    // degrees / edge weights (shared across both GCN layers)
    deg_init<<<NN / 256, 256, 0, stream>>>(dis);
    deg_acc<<<EE / 256, 256, 0, stream>>>(ea, ei, dis);
    deg_finish<<<NN / 256, 256, 0, stream>>>(dis);
    edge_w<<<EE / 256, 256, 0, stream>>>(ea, ei, dis, we);

    // GCN layer 1 GEMM first (consumes xn), then CSR build into the dead xn region
    gemm_tiled<64, 96, 32, 192, false, false, false><<<NN / 32, 192, 0, stream>>>(
        xn, conv1_w, nullptr, nullptr, nullptr, h1, 96, 0);

    hist_zero<<<NN / 256, 256, 0, stream>>>(cursor);
    hist_acc<<<EE / 256, 256, 0, stream>>>(ei, cursor);
    scan_kernel<<<1, 1024, 0, stream>>>(cursor, roff, cursor);
    csr_fill<<<EE / 256, 256, 0, stream>>>(ei, we, cursor, csr_src, csr_w);

    // aggregation (gather, no atomics), self-loop fused
    gcn_gather<24><<<NN * 24 / 256, 256, 0, stream>>>(h1, roff, csr_src, csr_w, dis, g1);

    // GCN layer 2: h2 = relu(g1+b1) @ W2 ; gather
    gemm_tiled<96, 64, 64, 256, true, false, false><<<NN / 64, 256, 0, stream>>>(
        g1, conv2_w, conv1_b, nullptr, nullptr, h2, 64, 0);
    gcn_gather<16><<<NN * 16 / 256, 256, 0, stream>>>(h2, roff, csr_src, csr_w, dis, g2);

    // LSTM input transform: xg[(s*T+t)*256 + g] = relu(g2+b2) @ w_ih^T + b_ih + b_hh
    // (xg overwrites the dead xn/csr/h1/g1 block)
    gemm_tiled<64, 128, 32, 256, true, true, true><<<NN / 32, 256, 0, stream>>>(
        g2, w_ih, conv2_b, b_ih, b_hh, xg, 256, 0);
    gemm_tiled<64, 128, 32, 256, true, true, true><<<NN / 32, 256, 0, stream>>>(
        g2, w_ih, conv2_b, b_ih, b_hh, xg, 256, 128);

    // LSTM recurrence
    lstm_kernel<<<SS / 4, 256, 0, stream>>>(xg, w_hh, hl);

    // FC head + softmax
    head_kernel<<<SS, 128, 0, stream>>>(hl, fc1_w, fc1_b, fc2_w, fc2_b, out);
}

// Round 3
// 757.983 us; speedup vs baseline: 5.2078x; 1.2002x over previous
//
#include <hip/hip_runtime.h>
#include <hip/hip_bf16.h>

#define NN 102400      // B*T*NODES
#define DD 64
#define EE 1638400
#define L1C 96
#define L2C 64
#define TT 32
#define NODESC 400
#define BB 8
#define SS 3200        // B*NODES
#define G4 256         // 4*D

// ---------------- workspace layout (floats) ----------------
// big block [0, 26,214,400): xn | a1 | g1 | ent(csr), later overwritten by xg
#define OFF_XN   ((size_t)0)          // NN*64
#define OFF_A1   ((size_t)6553600)    // NN*64
#define OFF_G1   ((size_t)13107200)   // NN*96 -> ends 22,937,600
#define OFF_ENT  ((size_t)22937600)   // EE int2 (2*EE floats) -> ends 26,214,400
#define OFF_XG   ((size_t)0)          // NN*256
#define OFF_H2   ((size_t)26214400)   // NN*64
#define OFF_G2   ((size_t)32768000)   // NN*64
#define OFF_DIS  ((size_t)39321600)   // NN
#define OFF_ROFF ((size_t)39424000)   // NN+1 ints (padded)
#define OFF_CUR  ((size_t)39526416)   // NN ints
#define OFF_HL   ((size_t)39628816)   // SS*64
#define OFF_ST   ((size_t)39833616)   // 256   -> total 39,833,872 floats = 159.3 MB

__device__ __forceinline__ void fma4(float4& a, float s, const float4& w) {
    a.x = fmaf(s, w.x, a.x); a.y = fmaf(s, w.y, a.y);
    a.z = fmaf(s, w.z, a.z); a.w = fmaf(s, w.w, a.w);
}
__device__ __forceinline__ float sigm(float x) { return 1.f / (1.f + __expf(-x)); }

// ---------------- normalization ----------------
__global__ void zero_stats(float* st) { if (threadIdx.x < 128) st[threadIdx.x] = 0.f; }

__global__ __launch_bounds__(256) void col_sums(const float* __restrict__ x, float* __restrict__ st) {
    int c = threadIdx.x & 63;
    size_t i = (size_t)blockIdx.x * 256 + threadIdx.x;
    size_t stride = (size_t)gridDim.x * 256;
    float s = 0.f, q = 0.f;
    for (size_t e = i; e < (size_t)NN * 64; e += stride) {
        float v = x[e]; s += v; q = fmaf(v, v, q);
    }
    __shared__ float ls[128];
    if (threadIdx.x < 128) ls[threadIdx.x] = 0.f;
    __syncthreads();
    atomicAdd(&ls[c], s); atomicAdd(&ls[64 + c], q);
    __syncthreads();
    if (threadIdx.x < 128) atomicAdd(&st[threadIdx.x], ls[threadIdx.x]);
}

__global__ void finalize_stats(float* st) {
    int c = threadIdx.x;
    if (c < 64) {
        float s = st[c], q = st[64 + c];
        float mean = s / (float)NN;
        float var = (q - s * s / (float)NN) / (float)(NN - 1);
        st[128 + c] = mean;
        st[192 + c] = rsqrtf(fmaxf(var, 1e-20f));
    }
}

__global__ __launch_bounds__(256) void normalize_k(const float* __restrict__ x, const float* __restrict__ st, float* __restrict__ xn) {
    size_t i = (size_t)blockIdx.x * 256 + threadIdx.x;   // float4 index
    int c = ((int)(i & 15)) * 4;
    float4 v = ((const float4*)x)[i];
    const float* mean = st + 128; const float* istd = st + 192;
    v.x = (v.x - mean[c + 0]) * istd[c + 0];
    v.y = (v.y - mean[c + 1]) * istd[c + 1];
    v.z = (v.z - mean[c + 2]) * istd[c + 2];
    v.w = (v.w - mean[c + 3]) * istd[c + 3];
    ((float4*)xn)[i] = v;
}

// ---------------- CSR build (dest-sorted, packed 8B entries, no float atomics) ----------------
__global__ void hist_zero(int* cnt) { cnt[blockIdx.x * 256 + threadIdx.x] = 0; }

__global__ void hist_acc(const int* __restrict__ ei, int* __restrict__ cnt) {
    int e = blockIdx.x * 256 + threadIdx.x;
    atomicAdd(&cnt[ei[EE + e]], 1);
}

// single-block exclusive scan over NN counts; writes roff[0..NN] and cursor[0..NN-1]
__global__ __launch_bounds__(1024) void scan_kernel(int* __restrict__ cnt, int* __restrict__ roff, int* __restrict__ cursor) {
    __shared__ int part[1024];
    int tid = threadIdx.x;
    int base = tid * (NN / 1024);
    int s = 0;
    for (int i = 0; i < NN / 1024; ++i) s += cnt[base + i];
    part[tid] = s;
    __syncthreads();
    for (int d = 1; d < 1024; d <<= 1) {
        int v = (tid >= d) ? part[tid - d] : 0;
        __syncthreads();
        part[tid] += v;
        __syncthreads();
    }
    int run = part[tid] - s;     // exclusive prefix of this thread's range
    for (int i = 0; i < NN / 1024; ++i) {
        int c = cnt[base + i];
        roff[base + i] = run;
        cursor[base + i] = run;
        run += c;
    }
    if (tid == 1023) roff[NN] = run;
}

__global__ void csr_fill(const int* __restrict__ ei, const float* __restrict__ ea,
                         int* __restrict__ cursor, int2* __restrict__ ent) {
    int e = blockIdx.x * 256 + threadIdx.x;
    int d = ei[EE + e];
    int pos = atomicAdd(&cursor[d], 1);
    ent[pos] = make_int2(ei[e], __float_as_int(fabsf(ea[2 * (size_t)e])));
}

// deg[n] = 1 + sum of raw weights in row n (self-loop weight 1); dis = rsqrt(deg)
__global__ void row_norm(const int* __restrict__ roff, const int2* __restrict__ ent, float* __restrict__ dis) {
    int n = blockIdx.x * 256 + threadIdx.x;
    int e0 = roff[n], e1 = roff[n + 1];
    float deg = 1.f;
    for (int e = e0; e < e1; ++e) deg += __int_as_float(ent[e].y);
    dis[n] = rsqrtf(deg);
}

// ---------------- tiled f32 GEMM ----------------
template<int K, int NC, int MB, int THREADS, bool PRELU, bool TRANSW, bool XGOUT>
__global__ __launch_bounds__(THREADS) void gemm_tiled(
    const float* __restrict__ A, const float* __restrict__ Wm,
    const float* __restrict__ bin, const float* __restrict__ bo1, const float* __restrict__ bo2,
    float* __restrict__ Cm, int ldC, int col0)
{
    __shared__ float As[MB * K];
    __shared__ float Ws[K * NC];

    if (!TRANSW) {
        for (int i = threadIdx.x; i < K * NC / 4; i += THREADS)
            ((float4*)Ws)[i] = ((const float4*)Wm)[i];
    } else {
        for (int i = threadIdx.x; i < NC * (K / 4); i += THREADS) {
            int g = i / (K / 4); int d = (i % (K / 4)) * 4;
            float4 v = *(const float4*)(Wm + (size_t)(col0 + g) * K + d);
            Ws[(d + 0) * NC + g] = v.x; Ws[(d + 1) * NC + g] = v.y;
            Ws[(d + 2) * NC + g] = v.z; Ws[(d + 3) * NC + g] = v.w;
        }
    }
    size_t row0 = (size_t)blockIdx.x * MB;
    for (int i = threadIdx.x; i < MB * (K / 4); i += THREADS) {
        int r = i / (K / 4); int c = (i % (K / 4)) * 4;
        float4 a = *(const float4*)(A + (row0 + r) * K + c);
        if (PRELU) {
            a.x = fmaxf(a.x + bin[c + 0], 0.f); a.y = fmaxf(a.y + bin[c + 1], 0.f);
            a.z = fmaxf(a.z + bin[c + 2], 0.f); a.w = fmaxf(a.w + bin[c + 3], 0.f);
        }
        ((float4*)As)[i] = a;
    }
    __syncthreads();

    constexpr int NCT = NC / 4;
    int tc = threadIdx.x % NCT;
    int tr = threadIdx.x / NCT;
    int r = tr * 4;
    float4 acc[4];
    acc[0] = acc[1] = acc[2] = acc[3] = make_float4(0.f, 0.f, 0.f, 0.f);

    #pragma unroll 8
    for (int d4 = 0; d4 < K / 4; ++d4) {
        float4 w0 = ((const float4*)Ws)[(4 * d4 + 0) * NCT + tc];
        float4 w1 = ((const float4*)Ws)[(4 * d4 + 1) * NCT + tc];
        float4 w2 = ((const float4*)Ws)[(4 * d4 + 2) * NCT + tc];
        float4 w3 = ((const float4*)Ws)[(4 * d4 + 3) * NCT + tc];
        #pragma unroll
        for (int i = 0; i < 4; ++i) {
            float4 av = ((const float4*)As)[(r + i) * (K / 4) + d4];
            fma4(acc[i], av.x, w0); fma4(acc[i], av.y, w1);
            fma4(acc[i], av.z, w2); fma4(acc[i], av.w, w3);
        }
    }

    if (!XGOUT) {
        #pragma unroll
        for (int i = 0; i < 4; ++i) {
            size_t row = row0 + r + i;
            *(float4*)(Cm + row * ldC + tc * 4) = acc[i];
        }
    } else {
        int cb = col0 + tc * 4;
        float4 bs;
        bs.x = bo1[cb + 0] + bo2[cb + 0]; bs.y = bo1[cb + 1] + bo2[cb + 1];
        bs.z = bo1[cb + 2] + bo2[cb + 2]; bs.w = bo1[cb + 3] + bo2[cb + 3];
        #pragma unroll
        for (int i = 0; i < 4; ++i) {
            int n = (int)row0 + r + i;                      // n = b*T*NODES + t*NODES + node
            int b_ = n / (TT * NODESC);
            int rem = n - b_ * (TT * NODESC);
            int t = rem / NODESC;
            int node = rem - t * NODESC;
            int orow = (b_ * NODESC + node) * TT + t;       // seq-major, time inner
            float4 o = acc[i];
            o.x += bs.x; o.y += bs.y; o.z += bs.z; o.w += bs.w;
            *(float4*)(Cm + (size_t)orow * ldC + cb) = o;
        }
    }
}

// ---------------- GCN aggregation: gather over packed CSR, dis folded in ----------------
// g[n] = dis[n] * ( dis[n]*h[n] + sum_e w_e*dis[src_e]*h[src_e] )
template<int C4>
__global__ __launch_bounds__(256) void gcn_gather(const float* __restrict__ h, const int* __restrict__ roff,
                                                  const int2* __restrict__ ent, const float* __restrict__ dis,
                                                  float* __restrict__ g) {
    unsigned int idx = blockIdx.x * 256 + threadIdx.x;
    unsigned int n = idx / C4, q = idx % C4;
    float dn = dis[n];
    float4 acc = ((const float4*)h)[(size_t)n * C4 + q];
    acc.x *= dn; acc.y *= dn; acc.z *= dn; acc.w *= dn;
    int e0 = roff[n], e1 = roff[n + 1];
    for (int e = e0; e < e1; ++e) {
        int2 en = ent[e];
        float w = __int_as_float(en.y) * dis[en.x];
        float4 v = ((const float4*)h)[(size_t)en.x * C4 + q];
        fma4(acc, w, v);
    }
    acc.x *= dn; acc.y *= dn; acc.z *= dn; acc.w *= dn;
    ((float4*)g)[(size_t)n * C4 + q] = acc;
}

// ---------------- LSTM (recurrent part; xg precomputed) ----------------
__global__ __launch_bounds__(256) void lstm_kernel(const float* __restrict__ xg, const float* __restrict__ whh,
                                                   float* __restrict__ hlast) {
    constexpr int QS = 4;
    __shared__ float hs[QS][64];
    __shared__ float cs[QS][64];
    __shared__ float gp[QS][256];
    int tid = threadIdx.x;
    int w = tid >> 6, j = tid & 63;
    int row = w * 64 + j;
    float4 wv[16];
    const float4* wr = (const float4*)(whh + (size_t)row * 64);
    #pragma unroll
    for (int d4 = 0; d4 < 16; ++d4) wv[d4] = wr[d4];
    hs[w][j] = 0.f; cs[w][j] = 0.f;
    __syncthreads();
    size_t s0 = (size_t)blockIdx.x * QS;
    for (int t = 0; t < TT; ++t) {
        #pragma unroll
        for (int q = 0; q < QS; ++q) {
            const float4* hq = (const float4*)hs[q];
            float4 acc = make_float4(0.f, 0.f, 0.f, 0.f);
            #pragma unroll
            for (int d4 = 0; d4 < 16; ++d4) {
                float4 hv = hq[d4];
                acc.x = fmaf(hv.x, wv[d4].x, acc.x); acc.y = fmaf(hv.y, wv[d4].y, acc.y);
                acc.z = fmaf(hv.z, wv[d4].z, acc.z); acc.w = fmaf(hv.w, wv[d4].w, acc.w);
            }
            float dot = (acc.x + acc.y) + (acc.z + acc.w);
            float pre = xg[((s0 + q) * TT + t) * G4 + row] + dot;
            gp[q][row] = pre;
        }
        __syncthreads();
        {
            int q = w;
            float gi = gp[q][j], gf = gp[q][64 + j], gg = gp[q][128 + j], go = gp[q][192 + j];
            float c = sigm(gf) * cs[q][j] + sigm(gi) * tanhf(gg);
            float h = sigm(go) * tanhf(c);
            cs[q][j] = c; hs[q][j] = h;
        }
        __syncthreads();
    }
    hlast[(s0 + w) * 64 + j] = hs[w][j];
}

// ---------------- FC head + softmax ----------------
__global__ __launch_bounds__(128) void head_kernel(const float* __restrict__ hl,
                                                   const float* __restrict__ w1, const float* __restrict__ b1,
                                                   const float* __restrict__ w2, const float* __restrict__ b2,
                                                   float* __restrict__ out) {
    __shared__ float hrow[64];
    __shared__ float a1[128];
    __shared__ float lg[3];
    int s = blockIdx.x, tid = threadIdx.x;
    if (tid < 64) hrow[tid] = hl[(size_t)s * 64 + tid];
    __syncthreads();
    {
        const float4* wr = (const float4*)(w1 + (size_t)tid * 64);
        const float4* hq = (const float4*)hrow;
        float4 acc = make_float4(0.f, 0.f, 0.f, 0.f);
        #pragma unroll
        for (int k = 0; k < 16; ++k) {
            float4 wv = wr[k]; float4 hv = hq[k];
            acc.x = fmaf(wv.x, hv.x, acc.x); acc.y = fmaf(wv.y, hv.y, acc.y);
            acc.z = fmaf(wv.z, hv.z, acc.z); acc.w = fmaf(wv.w, hv.w, acc.w);
        }
        a1[tid] = fmaxf((acc.x + acc.y) + (acc.z + acc.w) + b1[tid], 0.f);
    }
    __syncthreads();
    if (tid < 3) {
        const float4* wr = (const float4*)(w2 + (size_t)tid * 128);
        const float4* aq = (const float4*)a1;
        float4 acc = make_float4(0.f, 0.f, 0.f, 0.f);
        #pragma unroll
        for (int k = 0; k < 32; ++k) {
            float4 wv = wr[k]; float4 av = aq[k];
            acc.x = fmaf(wv.x, av.x, acc.x); acc.y = fmaf(wv.y, av.y, acc.y);
            acc.z = fmaf(wv.z, av.z, acc.z); acc.w = fmaf(wv.w, av.w, acc.w);
        }
        lg[tid] = (acc.x + acc.y) + (acc.z + acc.w) + b2[tid];
    }
    __syncthreads();
    if (tid == 0) {
        float m = fmaxf(lg[0], fmaxf(lg[1], lg[2]));
        float e0 = __expf(lg[0] - m), e1 = __expf(lg[1] - m), e2 = __expf(lg[2] - m);
        float inv = 1.f / (e0 + e1 + e2);
        out[(size_t)s * 3 + 0] = e0 * inv;
        out[(size_t)s * 3 + 1] = e1 * inv;
        out[(size_t)s * 3 + 2] = e2 * inv;
    }
}

extern "C" void kernel_launch(void* const* d_in, const int* in_sizes, int n_in,
                              void* d_out, int out_size, void* d_ws, size_t ws_size,
                              hipStream_t stream) {
    (void)in_sizes; (void)n_in; (void)out_size; (void)ws_size;
    const float* x        = (const float*)d_in[0];
    const float* ea       = (const float*)d_in[1];
    const float* conv1_w  = (const float*)d_in[2];
    const float* conv1_b  = (const float*)d_in[3];
    const float* conv2_w  = (const float*)d_in[4];
    const float* conv2_b  = (const float*)d_in[5];
    const float* w_ih     = (const float*)d_in[6];
    const float* w_hh     = (const float*)d_in[7];
    const float* b_ih     = (const float*)d_in[8];
    const float* b_hh     = (const float*)d_in[9];
    const float* fc1_w    = (const float*)d_in[10];
    const float* fc1_b    = (const float*)d_in[11];
    const float* fc2_w    = (const float*)d_in[12];
    const float* fc2_b    = (const float*)d_in[13];
    const int*   ei       = (const int*)d_in[14];
    float* out = (float*)d_out;

    float* W   = (float*)d_ws;
    float* xn  = W + OFF_XN;
    float* a1  = W + OFF_A1;
    float* g1  = W + OFF_G1;
    float* xg  = W + OFF_XG;
    float* h2  = W + OFF_H2;
    float* g2  = W + OFF_G2;
    float* dis = W + OFF_DIS;
    float* hl  = W + OFF_HL;
    float* st  = W + OFF_ST;
    int*   roff    = (int*)(W + OFF_ROFF);
    int*   cursor  = (int*)(W + OFF_CUR);
    int2*  ent     = (int2*)(W + OFF_ENT);

    // normalization
    zero_stats<<<1, 256, 0, stream>>>(st);
    col_sums<<<1024, 256, 0, stream>>>(x, st);
    finalize_stats<<<1, 64, 0, stream>>>(st);
    normalize_k<<<NN * 64 / 4 / 256, 256, 0, stream>>>(x, st, xn);

    // CSR build (dest-sorted, packed); raw |ea| weights
    hist_zero<<<NN / 256, 256, 0, stream>>>(cursor);
    hist_acc<<<EE / 256, 256, 0, stream>>>(ei, cursor);
    scan_kernel<<<1, 1024, 0, stream>>>(cursor, roff, cursor);
    csr_fill<<<EE / 256, 256, 0, stream>>>(ei, ea, cursor, ent);
    row_norm<<<NN / 256, 256, 0, stream>>>(roff, ent, dis);

    // GCN layer 1, commuted: a1 = S·xn (64 cols), then g1 = a1 @ W1 (96 cols)
    gcn_gather<16><<<NN * 16 / 256, 256, 0, stream>>>(xn, roff, ent, dis, a1);
    gemm_tiled<64, 96, 32, 192, false, false, false><<<NN / 32, 192, 0, stream>>>(
        a1, conv1_w, nullptr, nullptr, nullptr, g1, 96, 0);

    // GCN layer 2: h2 = relu(g1+b1) @ W2 (64 cols), then g2 = S·h2
    gemm_tiled<96, 64, 64, 256, true, false, false><<<NN / 64, 256, 0, stream>>>(
        g1, conv2_w, conv1_b, nullptr, nullptr, h2, 64, 0);
    gcn_gather<16><<<NN * 16 / 256, 256, 0, stream>>>(h2, roff, ent, dis, g2);

    // LSTM input transform: xg = relu(g2+b2) @ w_ih^T + b_ih + b_hh (overwrites big block)
    gemm_tiled<64, 128, 32, 256, true, true, true><<<NN / 32, 256, 0, stream>>>(
        g2, w_ih, conv2_b, b_ih, b_hh, xg, 256, 0);
    gemm_tiled<64, 128, 32, 256, true, true, true><<<NN / 32, 256, 0, stream>>>(
        g2, w_ih, conv2_b, b_ih, b_hh, xg, 256, 128);

    // LSTM recurrence
    lstm_kernel<<<SS / 4, 256, 0, stream>>>(xg, w_hh, hl);

    // FC head + softmax
    head_kernel<<<SS, 128, 0, stream>>>(hl, fc1_w, fc1_b, fc2_w, fc2_b, out);
}